// Round 15
// baseline (50.395 us; speedup 1.0000x reference)
//
#include <hip/hip_runtime.h>

#define PPB 4  // waves per 256-thread block (K2)

typedef float v2f __attribute__((ext_vector_type(2)));

__device__ __forceinline__ float frcp(float x) { return __builtin_amdgcn_rcpf(x); }

__device__ __forceinline__ v2f vfma2(v2f a, v2f b, v2f c) {
#if __has_builtin(__builtin_elementwise_fma)
  return __builtin_elementwise_fma(a, b, c);
#else
  v2f d; d.x = fmaf(a.x, b.x, c.x); d.y = fmaf(a.y, b.y, c.y); return d;
#endif
}
__device__ __forceinline__ v2f bc(float x) { v2f p; p.x = x; p.y = x; return p; }

// packed FastGRNN gate update (2 states per lane) — K2 only
__device__ __forceinline__ v2f gate2(v2f pre, v2f h, v2f bgB, v2f KB, v2f nzgB,
                                     v2f AB, bool first) {
  v2f a = pre + bgB;
  v2f s; s.x = __expf(-a.x); s.y = __expf(-a.y);
  v2f one = bc(1.f);
  v2f zd = s + one;
  v2f z; z.x = frcp(zd.x); z.y = frcp(zd.y);
  v2f u = (s * s) * KB;
  v2f cd = u + one;
  v2f cr; cr.x = frcp(cd.x); cr.y = frcp(cd.y);
  v2f cc = vfma2(cr, bc(2.f), bc(-1.f));
  v2f m = vfma2(z, nzgB, AB);
  v2f mc = m * cc;
  return first ? mc : vfma2(z, h, mc);
}

// ---------------- Kernel 0: wx = x . W1 once per pixel, dual layout (R12 verbatim) ----------------
__global__ __launch_bounds__(256) void wx_kernel(
    const float* __restrict__ inp, const float* __restrict__ W1,
    float* __restrict__ wxr, float* __restrict__ wxc) {
  const int tid = threadIdx.x, wv = tid >> 6, lane = tid & 63;
  const int p = lane >> 3, j = lane & 7;
  const int gw = blockIdx.x * 4 + wv;  // 3136 waves

  float w1c[16];
#pragma unroll
  for (int ci = 0; ci < 16; ++ci) w1c[ci] = W1[ci * 8 + j];

#pragma unroll 1
  for (int it = 0; it < 16; ++it) {
    const int pixel = (gw * 16 + it) * 8 + p;  // < 401408
    const float* src = inp + (size_t)pixel * 16;
    float4 x0 = ((const float4*)src)[0], x1 = ((const float4*)src)[1],
           x2 = ((const float4*)src)[2], x3 = ((const float4*)src)[3];
    float a = x0.x * w1c[0];
    a = fmaf(x0.y, w1c[1], a);
    a = fmaf(x0.z, w1c[2], a);
    a = fmaf(x0.w, w1c[3], a);
    a = fmaf(x1.x, w1c[4], a);
    a = fmaf(x1.y, w1c[5], a);
    a = fmaf(x1.z, w1c[6], a);
    a = fmaf(x1.w, w1c[7], a);
    a = fmaf(x2.x, w1c[8], a);
    a = fmaf(x2.y, w1c[9], a);
    a = fmaf(x2.z, w1c[10], a);
    a = fmaf(x2.w, w1c[11], a);
    a = fmaf(x3.x, w1c[12], a);
    a = fmaf(x3.y, w1c[13], a);
    a = fmaf(x3.z, w1c[14], a);
    a = fmaf(x3.w, w1c[15], a);
    wxr[(size_t)pixel * 8 + j] = a;
    const int b = pixel / 12544;
    const int rem = pixel - b * 12544;
    const int y = rem / 112, x = rem - y * 112;
    wxc[((size_t)(b * 112 + x) * 112 + y) * 8 + j] = a;
  }
}

// ---------------- Kernel A: level-1, lane = one full recurrence ----------------
// rid = ((b*27 + w)*112 + pos). wx for all 8 steps = 256B contiguous (wxr row
// mode / wxc col mode). Zero LDS, zero cross-lane; U1/biases uniform (SGPR).
__global__ __launch_bounds__(256) void l1_kernel(
    const float* __restrict__ wxr, const float* __restrict__ wxc,
    const float* __restrict__ U1, const float* __restrict__ bg1,
    const float* __restrict__ bu1, const float* __restrict__ zeta1,
    const float* __restrict__ nu1, float* __restrict__ hrowg,
    float* __restrict__ hcolg) {
  const int tid = threadIdx.x, wv = tid >> 6, lane = tid & 63;
  const int wid = blockIdx.x * 4 + wv;  // 0..3023
  const bool isrow = wid < 1512;
  const int rid = ((isrow ? wid : wid - 1512) << 6) + lane;  // < 96768
  const int pos = rid % 112;
  const int t1 = rid / 112;
  const int w = t1 % 27, b = t1 / 27;

  // prefetch all 64 wx floats (8 steps x 8 hid), contiguous 256B
  const float* src = (isrow ? wxr : wxc) +
                     (((size_t)(b * 112 + pos) * 112) + 4 * w) * 8;
  float4 c0 = ((const float4*)src)[0], c1 = ((const float4*)src)[1];
  float4 c2 = ((const float4*)src)[2], c3 = ((const float4*)src)[3];
  float4 c4 = ((const float4*)src)[4], c5 = ((const float4*)src)[5];
  float4 c6 = ((const float4*)src)[6], c7 = ((const float4*)src)[7];
  float4 c8 = ((const float4*)src)[8], c9 = ((const float4*)src)[9];
  float4 ca = ((const float4*)src)[10], cb = ((const float4*)src)[11];
  float4 cc4 = ((const float4*)src)[12], cd4 = ((const float4*)src)[13];
  float4 ce = ((const float4*)src)[14], cf = ((const float4*)src)[15];
  float wxv[64] = {
      c0.x, c0.y, c0.z, c0.w, c1.x, c1.y, c1.z, c1.w,
      c2.x, c2.y, c2.z, c2.w, c3.x, c3.y, c3.z, c3.w,
      c4.x, c4.y, c4.z, c4.w, c5.x, c5.y, c5.z, c5.w,
      c6.x, c6.y, c6.z, c6.w, c7.x, c7.y, c7.z, c7.w,
      c8.x, c8.y, c8.z, c8.w, c9.x, c9.y, c9.z, c9.w,
      ca.x, ca.y, ca.z, ca.w, cb.x, cb.y, cb.z, cb.w,
      cc4.x, cc4.y, cc4.z, cc4.w, cd4.x, cd4.y, cd4.z, cd4.w,
      ce.x, ce.y, ce.z, ce.w, cf.x, cf.y, cf.z, cf.w};

  // uniform recurrence weights (scalar loads -> SGPRs) — R8-K1 verbatim
  float u1r[8][8];
#pragma unroll
  for (int i = 0; i < 8; ++i)
#pragma unroll
    for (int j = 0; j < 8; ++j) u1r[i][j] = U1[i * 8 + j];
  float bgv[8], Kc[8];
#pragma unroll
  for (int j = 0; j < 8; ++j) {
    bgv[j] = bg1[j];
    Kc[j] = __expf(2.f * (bg1[j] - bu1[j]));
  }
  const float zg = frcp(1.f + __expf(-zeta1[0]));
  const float ng = frcp(1.f + __expf(-nu1[0]));
  const float A = zg + ng;

  float h[8];
  {  // t = 0 (h == 0)
#pragma unroll
    for (int j = 0; j < 8; ++j) {
      float s = __expf(-(wxv[j] + bgv[j]));
      float z = frcp(1.f + s);
      float u = s * s * Kc[j];
      float c = fmaf(2.f, frcp(1.f + u), -1.f);
      float m = fmaf(-zg, z, A);
      h[j] = m * c;
    }
  }
#pragma unroll
  for (int t = 1; t < 8; ++t) {
    float qa[8];
#pragma unroll
    for (int j = 0; j < 8; ++j) {
      float q = u1r[0][j] * h[0];
      q = fmaf(u1r[1][j], h[1], q);
      q = fmaf(u1r[2][j], h[2], q);
      q = fmaf(u1r[3][j], h[3], q);
      q = fmaf(u1r[4][j], h[4], q);
      q = fmaf(u1r[5][j], h[5], q);
      q = fmaf(u1r[6][j], h[6], q);
      q = fmaf(u1r[7][j], h[7], q);
      qa[j] = q;
    }
#pragma unroll
    for (int j = 0; j < 8; ++j) {
      float pre = wxv[t * 8 + j] + qa[j];
      float s = __expf(-(pre + bgv[j]));
      float z = frcp(1.f + s);
      float u = s * s * Kc[j];
      float c = fmaf(2.f, frcp(1.f + u), -1.f);
      float m = fmaf(-zg, z, A);
      h[j] = fmaf(z, h[j], m * c);
    }
  }

  float* dst = (isrow ? hrowg : hcolg) + (size_t)rid * 8;
  ((float4*)dst)[0] = float4{h[0], h[1], h[2], h[3]};
  ((float4*)dst)[1] = float4{h[4], h[5], h[6], h[7]};
}

// ---------------- Kernel B: level-2, 2 patches (packed) per wave (R6 verbatim) ----------------
__global__ __launch_bounds__(256) void l2_kernel(
    const float* __restrict__ hrowg, const float* __restrict__ hcolg,
    const float* __restrict__ W2, const float* __restrict__ U2,
    const float* __restrict__ bg2, const float* __restrict__ bu2,
    const float* __restrict__ zeta2, const float* __restrict__ nu2,
    float* __restrict__ out) {
  constexpr int GST = 18;  // h2 branch stride (v2 units)
  constexpr int WHT = 18;  // wh row stride (v2 units)
  __shared__ v2f hbI[PPB][128];
  __shared__ v2f whb[PPB][2 * 8 * WHT];
  __shared__ v2f h2I[PPB][3 * GST + 16];

  const int tid = threadIdx.x, wv = tid >> 6, lane = tid & 63;
  const int w = blockIdx.x * PPB + wv;
  const int n0 = 2 * w, n1 = n0 + 1;

  {
    const int p = lane >> 5, half = (lane >> 4) & 1, idx = lane & 15;
    const int pn = p ? n1 : n0;
    const int pw = pn % 27;
    const int qq = pn / 27;
    const int ph = qq % 27, bb = qq / 27;
    const float* src = half ? &hcolg[(((size_t)(bb * 27 + ph)) * 112 + pw * 4) * 8]
                            : &hrowg[(((size_t)(bb * 27 + pw)) * 112 + ph * 4) * 8];
    float4 val = ((const float4*)src)[idx];
    float* base = (float*)&hbI[wv][half * 64 + idx * 4];
    base[0 + p] = val.x;
    base[2 + p] = val.y;
    base[4 + p] = val.z;
    base[6 + p] = val.w;
  }
  __builtin_amdgcn_wave_barrier();

  const int g = lane >> 4, j = lane & 15;
  v2f w2b[8], u2b[16];
#pragma unroll
  for (int d = 0; d < 8; ++d) w2b[d] = bc(W2[d * 16 + j]);
#pragma unroll
  for (int i = 0; i < 16; ++i) u2b[i] = bc(U2[i * 16 + j]);
  const float bg2v = bg2[j], bu2v = bu2[j];
  const float zg2 = frcp(1.f + __expf(-zeta2[0]));
  const float ng2 = frcp(1.f + __expf(-nu2[0]));
  const v2f bgB = bc(bg2v);
  const v2f KB = bc(__expf(2.f * (bg2v - bu2v)));
  const v2f nzgB = bc(-zg2);
  const v2f AB = bc(zg2 + ng2);

  const int src = g >> 1;

  {
    const v2f* hb = &hbI[wv][src * 64];
    const int t0 = (g & 1) * 4;
#pragma unroll
    for (int i = 0; i < 4; ++i) {
      const int t = t0 + i;
      const v2f* hr = &hb[t * 8];
      v2f p = hr[0] * w2b[0];
#pragma unroll
      for (int d = 1; d < 8; ++d) p = vfma2(hr[d], w2b[d], p);
      whb[wv][(src * 8 + t) * WHT + j] = p;
    }
  }
  __builtin_amdgcn_wave_barrier();

  const v2f* whsrc = &whb[wv][src * 8 * WHT];
  v2f* h2q = &h2I[wv][g * GST];

  v2f h2 = bc(0.f);
  {
    const int tt = (g & 1) ? 7 : 0;
    v2f p = whsrc[tt * WHT + j];
    h2 = gate2(p, h2, bgB, KB, nzgB, AB, true);
    h2q[j] = h2;
  }
  __builtin_amdgcn_wave_barrier();
#pragma unroll
  for (int t = 1; t < 8; ++t) {
    const int tt = (g & 1) ? (7 - t) : t;
    v2f p = whsrc[tt * WHT + j];
    const float4* q4 = (const float4*)h2q;
    float4 v0 = q4[0], v1 = q4[1], v2_ = q4[2], v3 = q4[3];
    float4 v4 = q4[4], v5 = q4[5], v6 = q4[6], v7 = q4[7];
    v2f q = v2f{v0.x, v0.y} * u2b[0];
    q = vfma2(v2f{v0.z, v0.w}, u2b[1], q);
    q = vfma2(v2f{v1.x, v1.y}, u2b[2], q);
    q = vfma2(v2f{v1.z, v1.w}, u2b[3], q);
    q = vfma2(v2f{v2_.x, v2_.y}, u2b[4], q);
    q = vfma2(v2f{v2_.z, v2_.w}, u2b[5], q);
    q = vfma2(v2f{v3.x, v3.y}, u2b[6], q);
    q = vfma2(v2f{v3.z, v3.w}, u2b[7], q);
    q = vfma2(v2f{v4.x, v4.y}, u2b[8], q);
    q = vfma2(v2f{v4.z, v4.w}, u2b[9], q);
    q = vfma2(v2f{v5.x, v5.y}, u2b[10], q);
    q = vfma2(v2f{v5.z, v5.w}, u2b[11], q);
    q = vfma2(v2f{v6.x, v6.y}, u2b[12], q);
    q = vfma2(v2f{v6.z, v6.w}, u2b[13], q);
    q = vfma2(v2f{v7.x, v7.y}, u2b[14], q);
    q = vfma2(v2f{v7.z, v7.w}, u2b[15], q);
    v2f pre = p + q;
    h2 = gate2(pre, h2, bgB, KB, nzgB, AB, false);
    if (t < 7) {
      h2q[j] = h2;
      __builtin_amdgcn_wave_barrier();
    }
  }

  out[(size_t)n0 * 64 + lane] = h2.x;
  out[(size_t)n1 * 64 + lane] = h2.y;
}

extern "C" void kernel_launch(void* const* d_in, const int* in_sizes, int n_in,
                              void* d_out, int out_size, void* d_ws, size_t ws_size,
                              hipStream_t stream) {
  const float* inp   = (const float*)d_in[0];
  const float* W1    = (const float*)d_in[1];
  const float* U1    = (const float*)d_in[2];
  const float* bg1   = (const float*)d_in[3];
  const float* bu1   = (const float*)d_in[4];
  const float* zeta1 = (const float*)d_in[5];
  const float* nu1   = (const float*)d_in[6];
  const float* W2    = (const float*)d_in[7];
  const float* U2    = (const float*)d_in[8];
  const float* bg2   = (const float*)d_in[9];
  const float* bu2   = (const float*)d_in[10];
  const float* zeta2 = (const float*)d_in[11];
  const float* nu2   = (const float*)d_in[12];
  float* out = (float*)d_out;

  const size_t WXSZ = (size_t)32 * 112 * 112 * 8;  // 3211264 floats
  const size_t HSZ = (size_t)32 * 27 * 112 * 8;    // 774144 floats
  float* wxr = (float*)d_ws;
  float* wxc = wxr + WXSZ;
  float* hrowg = wxc + WXSZ;
  float* hcolg = hrowg + HSZ;

  // K0: 401408 pixel GEMVs, dual layout
  wx_kernel<<<dim3(784), dim3(256), 0, stream>>>(inp, W1, wxr, wxc);
  // K1: 193536 recurrences, 64/wave, 4 waves/block -> 756 blocks
  l1_kernel<<<dim3(756), dim3(256), 0, stream>>>(
      wxr, wxc, U1, bg1, bu1, zeta1, nu1, hrowg, hcolg);
  // K2: 11664 patch-pair waves, 4/block
  l2_kernel<<<dim3(2916), dim3(256), 0, stream>>>(
      hrowg, hcolg, W2, U2, bg2, bu2, zeta2, nu2, out);
}